// Round 13
// baseline (324.462 us; speedup 1.0000x reference)
//
#include <hip/hip_runtime.h>
#include <math.h>

#define NV 32768
#define CD 128
#define NCLS 10
#define KSEL 500
#define BNEPS 1e-5f
#define NK (NCLS * NV)          // 327680 keys per batch
#define H20CUT 0x3E000          // (s>>12) floor for score >= 0.125
#define H20BINS 6144            // (0x3F800 - 0x3E000); sigmoid < 1.0
#define CANDCAP 2048
#define NP 32                   // histogram/filter chunks per batch
#define PCHUNKV (NK / NP)       // 10240 keys per chunk
#define PCHUNK4 (PCHUNKV / 4)   // 2560 uint4 per chunk
#define LCAP 512                // per-block LDS candidate list capacity

// ---------------------------------------------------------------------------
// Stage A: hm head over all voxels. 64 rows x 128 cols per block (256 thr),
// 2048 blocks, 8 rows x 4 cols per thread (r11/r12 confirmed geometry).
// KEY CHANGE vs r12: LDS trimmed 38.4 KB -> exactly 32 KB -> 5 blocks/CU
// (20 waves, was 16). w2s/b2s LDS dropped (GEMM2 reads the 5 KB W2 table
// straight from global/L1 — same values, same c order); the act tile reuses
// the 32 KB swizzled float4 layout (act = 64x128 floats exactly), written
// as float4 (also removes the scalar stride-129 store bank collisions).
// fmaf order per (row,col) k-ascending and GEMM2 per-(r,o) c-ascending on
// identical values -> bitwise identical scores.
// ---------------------------------------------------------------------------
__global__ __launch_bounds__(256, 5) void stageA_kernel(
    const float* __restrict__ feats,
    const float* __restrict__ W1,
    const float* __restrict__ b1,
    const float* __restrict__ bng,
    const float* __restrict__ bnb,
    const float* __restrict__ bnm,
    const float* __restrict__ bnv,
    const float* __restrict__ W2hm,
    const float* __restrict__ b2hm,
    unsigned int* __restrict__ scoreb)
{
    // 32 KB union: swizzled feats (8192 floats) / swizzled act (8192 floats)
    __shared__ __align__(16) float smem[64 * 128];
    float4* const fsmv = (float4*)smem;

    const int tid = threadIdx.x;
    const int gbase = blockIdx.x * 64;

    // feats tile -> LDS, swizzled: (r, float4-group g) at fsmv[r*32 + (g^(r&31))]
    for (int t = tid; t < 64 * 32; t += 256) {
        const int r = t >> 5;
        const int g = t & 31;
        const float4 v = *(const float4*)(feats + (((size_t)(gbase + r)) << 7) + (g << 2));
        fsmv[r * 32 + (g ^ (r & 31))] = v;
    }
    __syncthreads();

    const int c0 = (tid & 31) << 2;   // 4 output cols (32 col groups)
    const int r0 = (tid >> 5) << 3;   // 8 rows (8 row groups -> 64 rows)
    const float* const Wc0 = W1 + c0;

    float acc[8][4];
    #pragma unroll
    for (int i = 0; i < 8; ++i)
        #pragma unroll
        for (int j = 0; j < 4; ++j) acc[i][j] = 0.f;

    float4 wA[4], wB[4];

    // ---- prologue: W for k-chunk 0 into set A ----
    #pragma unroll
    for (int kk = 0; kk < 4; ++kk)
        wA[kk] = *(const float4*)(Wc0 + (kk << 7));

#define SA_PREFETCH_W(WW, KC)                                             \
    {                                                                     \
        const int kb_ = (KC) << 2;                                        \
        _Pragma("unroll")                                                 \
        for (int kk = 0; kk < 4; ++kk)                                    \
            WW[kk] = *(const float4*)(Wc0 + ((kb_ + kk) << 7));           \
    }

#define SA_COMPUTE(WW, KC)                                                \
    {                                                                     \
        const int kc_ = (KC);                                             \
        float4 fr[8];                                                     \
        _Pragma("unroll")                                                 \
        for (int i = 0; i < 8; ++i) {                                     \
            const int row = r0 + i;                                       \
            fr[i] = fsmv[row * 32 + (kc_ ^ (row & 31))];                  \
        }                                                                 \
        const float* frp = (const float*)fr;                              \
        const float* wp  = (const float*)WW;                              \
        _Pragma("unroll")                                                 \
        for (int kk = 0; kk < 4; ++kk)                                    \
            _Pragma("unroll")                                             \
            for (int ri = 0; ri < 8; ++ri) {                              \
                const float f = frp[ri * 4 + kk];                         \
                _Pragma("unroll")                                         \
                for (int ci = 0; ci < 4; ++ci)                            \
                    acc[ri][ci] = fmaf(f, wp[kk * 4 + ci], acc[ri][ci]);  \
            }                                                             \
    }

    for (int kc = 0; kc < 32; kc += 2) {
        SA_PREFETCH_W(wB, kc + 1)               // kc+1 <= 31 always
        SA_COMPUTE(wA, kc)                      // chunk kc (fr inline)
        SA_PREFETCH_W(wA, (kc + 2) & 31)        // last iter reloads 0 (unused)
        SA_COMPUTE(wB, kc + 1)                  // chunk kc+1
    }
#undef SA_PREFETCH_W
#undef SA_COMPUTE

    __syncthreads(); // all fsm reads done before overwrite with act

    // BN (eval) + ReLU  (identical formulas/order per (row,col))
    #pragma unroll
    for (int ci = 0; ci < 4; ++ci) {
        const int c = c0 + ci;
        const float inv = bng[c] / sqrtf(bnv[c] + BNEPS);
        const float mu = bnm[c];
        const float be = bnb[c];
        const float bb = b1[c];
        #pragma unroll
        for (int ri = 0; ri < 8; ++ri) {
            const float h = (acc[ri][ci] + bb - mu) * inv + be;
            acc[ri][ci] = fmaxf(h, 0.f);
        }
    }
    // act tile -> LDS in the SAME swizzled float4 layout (g = tid&31)
    {
        const int g = tid & 31;
        #pragma unroll
        for (int ri = 0; ri < 8; ++ri) {
            const int row = r0 + ri;
            float4 av;
            av.x = acc[ri][0]; av.y = acc[ri][1];
            av.z = acc[ri][2]; av.w = acc[ri][3];
            fsmv[row * 32 + (g ^ (row & 31))] = av;
        }
    }
    __syncthreads();

    // GEMM2: logits[r][o] = sum_c act[r][c] * W2[c][o]; c ascending
    // (group-major float4 reads preserve the exact per-(r,o) fmaf chain).
    const int r = tid & 63;
    const int ogrp = tid >> 6;  // wave-uniform
    float lg[3] = {0.f, 0.f, 0.f};
    for (int g = 0; g < 32; ++g) {
        const float4 av = fsmv[r * 32 + (g ^ (r & 31))];
        const float a4[4] = {av.x, av.y, av.z, av.w};
        #pragma unroll
        for (int cc = 0; cc < 4; ++cc) {
            const int c = (g << 2) + cc;
            const float a = a4[cc];
            #pragma unroll
            for (int i = 0; i < 3; ++i) {
                const int o = ogrp + 4 * i;
                if (o < NCLS) lg[i] = fmaf(a, W2hm[c * NCLS + o], lg[i]);
            }
        }
    }
    const int n = gbase + r;
    const int b = n >> 15;          // NV = 2^15
    const int v = n & (NV - 1);
    unsigned int* sb = scoreb + (size_t)b * NK;
    #pragma unroll
    for (int i = 0; i < 3; ++i) {
        const int o = ogrp + 4 * i;
        if (o < NCLS) {
            const float x = lg[i] + b2hm[o];
            const float s = 1.f / (1.f + expf(-x));
            sb[o * NV + v] = __float_as_uint(s);
        }
    }
}

// ---------------------------------------------------------------------------
// Stage B1: per-chunk PARTIAL 20-bit histograms, plain stores (no global
// atomics, no zeroing kernel). grid (NP, B) = 128 blocks.
// ---------------------------------------------------------------------------
__global__ __launch_bounds__(256) void stageB1_kernel(
    const unsigned int* __restrict__ scoreb,
    unsigned int* __restrict__ hist_part)
{
    __shared__ unsigned int lh[H20BINS];
    const int tid = threadIdx.x;
    const int b = blockIdx.y;
    const uint4* sb4 = (const uint4*)(scoreb + (size_t)b * NK) + (size_t)blockIdx.x * PCHUNK4;

    for (int i = tid; i < H20BINS; i += 256) lh[i] = 0u;
    __syncthreads();

    #pragma unroll
    for (int q = 0; q < 10; ++q) {                // 10*256 = 2560 uint4
        const uint4 v = sb4[q * 256 + tid];
        const unsigned int sv[4] = {v.x, v.y, v.z, v.w};
        #pragma unroll
        for (int k = 0; k < 4; ++k) {
            const int rel = (int)(sv[k] >> 12) - H20CUT;
            if (rel >= 0) atomicAdd(&lh[rel], 1u);
        }
    }
    __syncthreads();

    unsigned int* gh = hist_part + ((size_t)b * NP + blockIdx.x) * H20BINS;
    for (int i = tid; i < H20BINS; i += 256) gh[i] = lh[i];   // ALL bins
}

// ---------------------------------------------------------------------------
// Stage B2: sum partials + suffix-scan -> threshold T (20-bit truncated).
// grid (B), 1024 thr. Also zeroes cnt[b]. Deterministic (fixed sum order).
// ---------------------------------------------------------------------------
__global__ __launch_bounds__(1024) void stageB2_kernel(
    const unsigned int* __restrict__ hist_part,
    unsigned int* __restrict__ Tbuf,
    unsigned int* __restrict__ cnt)
{
    __shared__ unsigned int part[1024];
    __shared__ unsigned int sT;
    const int b = blockIdx.x;
    const int tid = threadIdx.x;  // owns bins [tid*6, tid*6+6)

    unsigned int loc[6] = {0u, 0u, 0u, 0u, 0u, 0u};
    const unsigned int* hp = hist_part + (size_t)b * NP * H20BINS;
    for (int p = 0; p < NP; ++p) {
        const unsigned int* hq = hp + (size_t)p * H20BINS + tid * 6;
        #pragma unroll
        for (int i = 0; i < 6; ++i) loc[i] += hq[i];
    }
    unsigned int Ls = 0;
    #pragma unroll
    for (int i = 0; i < 6; ++i) Ls += loc[i];
    part[tid] = Ls;
    __syncthreads();

    // inclusive suffix scan over 1024 partials (Hillis-Steele, 10 steps)
    for (int off = 1; off < 1024; off <<= 1) {
        const unsigned int add = (tid + off < 1024) ? part[tid + off] : 0u;
        __syncthreads();
        part[tid] += add;
        __syncthreads();
    }
    const unsigned int incl = part[tid];          // sum of segments >= tid
    const unsigned int above_seg = incl - Ls;     // sum of segments  > tid

    if (above_seg < KSEL && incl >= KSEL) {       // exactly one thread
        int above = (int)above_seg;
        int tbin = -1;
        #pragma unroll
        for (int i = 5; i >= 0; --i) {
            const int cbin = (int)loc[i];
            if (tbin < 0) {
                if (above + cbin >= KSEL) tbin = tid * 6 + i;
                else above += cbin;
            }
        }
        sT = ((unsigned int)(tbin + H20CUT)) << 12;
    }
    if (tid == 0 && part[0] < KSEL) sT = ((unsigned int)H20CUT) << 12;  // degenerate
    __syncthreads();
    if (tid == 0) {
        Tbuf[b] = sT;
        cnt[b] = 0u;
    }
}

// ---------------------------------------------------------------------------
// Stage B3: filter s >= T, per-block LDS aggregation -> ONE global atomic
// per block. grid (NP, B) = 128 blocks.
// ---------------------------------------------------------------------------
__global__ __launch_bounds__(256) void stageB3_kernel(
    const unsigned int* __restrict__ scoreb,
    const unsigned int* __restrict__ Tbuf,
    unsigned int* __restrict__ cnt,
    unsigned long long* __restrict__ cand)
{
    __shared__ unsigned long long lbuf[LCAP];
    __shared__ unsigned int lcnt;
    __shared__ unsigned int sbase;
    const int tid = threadIdx.x;
    const int b = blockIdx.y;
    const unsigned int T = Tbuf[b];
    const uint4* sb4 = (const uint4*)(scoreb + (size_t)b * NK) + (size_t)blockIdx.x * PCHUNK4;
    unsigned long long* cb = cand + (size_t)b * CANDCAP;

    if (tid == 0) lcnt = 0u;
    __syncthreads();

    #pragma unroll
    for (int q = 0; q < 10; ++q) {
        const int vi = q * 256 + tid;
        const uint4 v = sb4[vi];
        const unsigned int sv[4] = {v.x, v.y, v.z, v.w};
        const unsigned int i0 = (unsigned int)((blockIdx.x * PCHUNK4 + vi) * 4);
        #pragma unroll
        for (int k = 0; k < 4; ++k) {
            if (sv[k] >= T) {
                const unsigned long long key =
                    ((unsigned long long)sv[k] << 32) |
                    (unsigned long long)(0xFFFFFFFFu - (i0 + k));
                const unsigned int p = atomicAdd(&lcnt, 1u);
                if (p < LCAP) {
                    lbuf[p] = key;
                } else {                           // overflow: direct global
                    const unsigned int gp = atomicAdd(&cnt[b], 1u);
                    if (gp < CANDCAP) cb[gp] = key;
                }
            }
        }
    }
    __syncthreads();
    const unsigned int nloc = min(lcnt, (unsigned int)LCAP);
    if (tid == 0) sbase = (nloc > 0u) ? atomicAdd(&cnt[b], nloc) : 0u;
    __syncthreads();
    const unsigned int base = sbase;
    for (unsigned int i = tid; i < nloc; i += 256) {
        const unsigned int pos = base + i;
        if (pos < CANDCAP) cb[pos] = lbuf[i];
    }
}

// ---------------------------------------------------------------------------
// Stage B4: bitonic sort candidates desc (sized to count), emit top-500.
// grid (B), 1024 thr.
// ---------------------------------------------------------------------------
__global__ __launch_bounds__(1024) void stageB4_kernel(
    const unsigned long long* __restrict__ cand,
    const unsigned int* __restrict__ cnt,
    float* __restrict__ sel_score,
    int* __restrict__ sel_cls,
    int* __restrict__ sel_vox)
{
    __shared__ unsigned long long kbuf[CANDCAP];
    const int b = blockIdx.x;
    const int tid = threadIdx.x;
    const int n = min((int)cnt[b], CANDCAP);
    int m = 512;
    while (m < n) m <<= 1;
    for (int i = tid; i < m; i += 1024)
        kbuf[i] = (i < n) ? cand[(size_t)b * CANDCAP + i] : 0ull;
    __syncthreads();
    for (int size = 2; size <= m; size <<= 1) {
        for (int stride = size >> 1; stride > 0; stride >>= 1) {
            for (int j = tid; j < m; j += 1024) {
                const int p = j ^ stride;
                if (p > j) {
                    const unsigned long long x = kbuf[j];
                    const unsigned long long y = kbuf[p];
                    const bool descRegion = ((j & size) == 0);
                    if ((x < y) == descRegion) { kbuf[j] = y; kbuf[p] = x; }
                }
            }
            __syncthreads();
        }
    }
    if (tid < KSEL) {
        const unsigned long long kk = kbuf[tid];
        const unsigned int s32 = (unsigned int)(kk >> 32);
        const unsigned int fl = 0xFFFFFFFFu - (unsigned int)(kk & 0xFFFFFFFFull);
        const int idx = b * KSEL + tid;
        sel_score[idx] = __uint_as_float(s32);
        sel_cls[idx] = (int)(fl >> 15);
        sel_vox[idx] = (int)(fl & (NV - 1));
    }
}

// ---------------------------------------------------------------------------
// Stage C+D fused, head-parallel: 640 threads = 5 heads x 128 cols; all 5
// head-GEMMs run concurrently. GEMM2 = 40 parallel 128-dots. Per-(row,col)
// k/cc order identical to the verified version -> bitwise identical.
// ---------------------------------------------------------------------------
__global__ __launch_bounds__(640) void stageCD_kernel(
    const float* __restrict__ feats,
    const int* __restrict__ voxel_xy,
    const float* __restrict__ sel_score,
    const int* __restrict__ sel_cls,
    const int* __restrict__ sel_vox,
    const float* __restrict__ W1,
    const float* __restrict__ b1,
    const float* __restrict__ bng,
    const float* __restrict__ bnb,
    const float* __restrict__ bnm,
    const float* __restrict__ bnv,
    const float* __restrict__ W2c, const float* __restrict__ b2c,
    const float* __restrict__ W2z, const float* __restrict__ b2z,
    const float* __restrict__ W2d, const float* __restrict__ b2d,
    const float* __restrict__ W2r, const float* __restrict__ b2r,
    const float* __restrict__ W2v, const float* __restrict__ b2v,
    float* __restrict__ out,
    int total)
{
    __shared__ float fs[4][128];
    __shared__ float as_[5][4][128];
    __shared__ float dec_s[4][10];
    __shared__ int vsel[4];
    const int tid = threadIdx.x;
    const int s0 = blockIdx.x * 4;

    if (tid < 4) {
        const int s = s0 + tid;
        vsel[tid] = (s / KSEL) * NV + sel_vox[s];
    }
    __syncthreads();
    if (tid < 512) {
        const int j = tid >> 7;
        const int c = tid & 127;
        fs[j][c] = feats[((size_t)vsel[j] << 7) + c];
    }
    __syncthreads();

    // ---- GEMM1 + BN + ReLU, all 5 heads concurrent ----
    {
        const int h = tid / 128;       // 0..4 (wave-uniform: 128 = 2 waves)
        const int c = tid & 127;
        const int head = h + 1;
        float acc[4] = {0.f, 0.f, 0.f, 0.f};
        const float* Wh = W1 + head * (CD * CD) + c;
        for (int k = 0; k < 128; ++k) {
            const float w = Wh[k << 7];
            #pragma unroll
            for (int j = 0; j < 4; ++j)
                acc[j] = fmaf(fs[j][k], w, acc[j]);
        }
        const int hc = head * CD + c;
        const float inv = bng[hc] / sqrtf(bnv[hc] + BNEPS);
        const float mu = bnm[hc], be = bnb[hc], bb = b1[hc];
        #pragma unroll
        for (int j = 0; j < 4; ++j) {
            const float hv = (acc[j] + bb - mu) * inv + be;
            as_[h][j][c] = fmaxf(hv, 0.f);
        }
    }
    __syncthreads();

    // ---- GEMM2: 40 independent 128-dots (row j, output slot) ----
    if (tid < 40) {
        const int j = tid / 10;
        const int slot = tid % 10;
        const float* w2; const float* bb2; int hh, o, oc; bool ex = false;
        if (slot < 2)      { w2 = W2c; bb2 = b2c; hh = 0; o = slot;     oc = 2; }
        else if (slot < 3) { w2 = W2z; bb2 = b2z; hh = 1; o = 0;        oc = 1; }
        else if (slot < 6) { w2 = W2d; bb2 = b2d; hh = 2; o = slot - 3; oc = 3; ex = true; }
        else if (slot < 8) { w2 = W2r; bb2 = b2r; hh = 3; o = slot - 6; oc = 2; }
        else               { w2 = W2v; bb2 = b2v; hh = 4; o = slot - 8; oc = 2; }
        float a = 0.f;
        for (int cc = 0; cc < 128; ++cc)
            a = fmaf(as_[hh][j][cc], w2[cc * oc + o], a);
        a += bb2[o];
        if (ex) a = expf(a);
        dec_s[j][slot] = a;
    }
    __syncthreads();

    // ---- decode (stageD formulas, bitwise identical) ----
    if (tid < 4) {
        const int s = s0 + tid;
        const int b = s / KSEL;
        const float score = sel_score[s];
        const int cls = sel_cls[s];
        const int v = sel_vox[s];
        const int n = b * NV + v;
        const float xi = (float)voxel_xy[2 * n];
        const float yi = (float)voxel_xy[2 * n + 1];
        const float* dd = dec_s[tid];
        const float cx = dd[0], cy = dd[1], cz = dd[2];
        const float d0 = dd[3], d1 = dd[4], d2 = dd[5];
        const float rc = dd[6], rs = dd[7], ve0 = dd[8], ve1 = dd[9];
        const float SV = 0.075f * 8.0f;
        const float xs = (xi + cx) * SV + (-54.0f);
        const float ys = (yi + cy) * SV + (-54.0f);
        const float ang = atan2f(rs, rc);
        const bool mk = (xs >= -61.2f) && (ys >= -61.2f) && (cz >= -10.0f) &&
                        (xs <= 61.2f) && (ys <= 61.2f) && (cz <= 10.0f) &&
                        (score > 0.1f);
        const float m = mk ? 1.f : 0.f;
        float* bx = out + (size_t)s * 10;
        bx[0] = xs * m; bx[1] = ys * m; bx[2] = cz * m;
        bx[3] = d0 * m; bx[4] = d1 * m; bx[5] = d2 * m;
        bx[6] = ang * m; bx[7] = ve0 * m; bx[8] = ve1 * m; bx[9] = score * m;
        out[(size_t)total * 10 + s] = mk ? (float)(cls + 1) : 0.f;
        out[(size_t)total * 11 + s] = (float)n;
        out[(size_t)total * 12 + s] = m;
    }
}

extern "C" void kernel_launch(void* const* d_in, const int* in_sizes, int n_in,
                              void* d_out, int out_size, void* d_ws, size_t ws_size,
                              hipStream_t stream) {
    const float* feats   = (const float*)d_in[0];
    const int*   voxelxy = (const int*)d_in[1];
    const float* W1   = (const float*)d_in[2];
    const float* b1   = (const float*)d_in[3];
    const float* bng  = (const float*)d_in[4];
    const float* bnb  = (const float*)d_in[5];
    const float* bnm  = (const float*)d_in[6];
    const float* bnv  = (const float*)d_in[7];
    const float* W2hm = (const float*)d_in[8];
    const float* b2hm = (const float*)d_in[9];
    const float* W2c  = (const float*)d_in[10];
    const float* b2c  = (const float*)d_in[11];
    const float* W2z  = (const float*)d_in[12];
    const float* b2z  = (const float*)d_in[13];
    const float* W2d  = (const float*)d_in[14];
    const float* b2d  = (const float*)d_in[15];
    const float* W2r  = (const float*)d_in[16];
    const float* b2r  = (const float*)d_in[17];
    const float* W2v  = (const float*)d_in[18];
    const float* b2v  = (const float*)d_in[19];

    const int B = in_sizes[0] / (NV * CD);
    const int N = B * NV;
    const int total = B * KSEL;

    // workspace layout (8-byte aligned blocks)
    char* ws = (char*)d_ws;
    unsigned int* scoreb    = (unsigned int*)ws;         ws += (size_t)B * NK * 4;
    unsigned int* hist_part = (unsigned int*)ws;         ws += (size_t)B * NP * H20BINS * 4;
    unsigned int* cnt       = (unsigned int*)ws;         ws += 8 * 4;
    unsigned int* Tbuf      = (unsigned int*)ws;         ws += 8 * 4;
    unsigned long long* cand = (unsigned long long*)ws;  ws += (size_t)B * CANDCAP * 8;
    float* sel_score = (float*)ws;                       ws += (size_t)total * 4;
    int*   sel_cls   = (int*)ws;                         ws += (size_t)total * 4;
    int*   sel_vox   = (int*)ws;                         ws += (size_t)total * 4;

    stageA_kernel<<<dim3(N / 64), dim3(256), 0, stream>>>(
        feats, W1, b1, bng, bnb, bnm, bnv, W2hm, b2hm, scoreb);

    stageB1_kernel<<<dim3(NP, B), dim3(256), 0, stream>>>(scoreb, hist_part);
    stageB2_kernel<<<dim3(B), dim3(1024), 0, stream>>>(hist_part, Tbuf, cnt);
    stageB3_kernel<<<dim3(NP, B), dim3(256), 0, stream>>>(scoreb, Tbuf, cnt, cand);
    stageB4_kernel<<<dim3(B), dim3(1024), 0, stream>>>(
        cand, cnt, sel_score, sel_cls, sel_vox);

    stageCD_kernel<<<dim3(total / 4), dim3(640), 0, stream>>>(
        feats, voxelxy, sel_score, sel_cls, sel_vox,
        W1, b1, bng, bnb, bnm, bnv,
        W2c, b2c, W2z, b2z, W2d, b2d, W2r, b2r, W2v, b2v,
        (float*)d_out, total);
}

// Round 14
// 291.011 us; speedup vs baseline: 1.1149x; 1.1149x over previous
//
#include <hip/hip_runtime.h>
#include <math.h>

#define NV 32768
#define CD 128
#define NCLS 10
#define KSEL 500
#define BNEPS 1e-5f
#define NK (NCLS * NV)          // 327680 keys per batch
#define H20CUT 0x3E000          // (s>>12) floor for score >= 0.125
#define H20BINS 6144            // (0x3F800 - 0x3E000); sigmoid < 1.0
#define CANDCAP 2048
#define NP 32                   // histogram/filter chunks per batch
#define PCHUNKV (NK / NP)       // 10240 keys per chunk
#define PCHUNK4 (PCHUNKV / 4)   // 2560 uint4 per chunk
#define LCAP 512                // per-block LDS candidate list capacity

// ---------------------------------------------------------------------------
// Stage A: hm head over all voxels. 64 rows x 128 cols per block (256 thr),
// 2048 blocks, 8 rows x 4 cols per thread (r11/r12 confirmed geometry).
// r13's 32 KB LDS layout kept (zero bank conflicts, float4 act stores,
// 5 blocks/CU by LDS) but with __launch_bounds__(256, 4): r13's ",5"
// squeezed the allocator to 48 VGPR -> massive spill (WRITE 48 MB).
// ",4" restores the r12 register regime (64 VGPR, no spill); occupancy
// is then LDS-limited at 5 blocks/CU (160/32), giving the +25% wave
// count without the spill. fmaf order per (row,col) k-ascending and
// GEMM2 per-(r,o) c-ascending on identical values -> bitwise identical.
// ---------------------------------------------------------------------------
__global__ __launch_bounds__(256, 4) void stageA_kernel(
    const float* __restrict__ feats,
    const float* __restrict__ W1,
    const float* __restrict__ b1,
    const float* __restrict__ bng,
    const float* __restrict__ bnb,
    const float* __restrict__ bnm,
    const float* __restrict__ bnv,
    const float* __restrict__ W2hm,
    const float* __restrict__ b2hm,
    unsigned int* __restrict__ scoreb)
{
    // 32 KB union: swizzled feats (8192 floats) / swizzled act (8192 floats)
    __shared__ __align__(16) float smem[64 * 128];
    float4* const fsmv = (float4*)smem;

    const int tid = threadIdx.x;
    const int gbase = blockIdx.x * 64;

    // feats tile -> LDS, swizzled: (r, float4-group g) at fsmv[r*32 + (g^(r&31))]
    for (int t = tid; t < 64 * 32; t += 256) {
        const int r = t >> 5;
        const int g = t & 31;
        const float4 v = *(const float4*)(feats + (((size_t)(gbase + r)) << 7) + (g << 2));
        fsmv[r * 32 + (g ^ (r & 31))] = v;
    }
    __syncthreads();

    const int c0 = (tid & 31) << 2;   // 4 output cols (32 col groups)
    const int r0 = (tid >> 5) << 3;   // 8 rows (8 row groups -> 64 rows)
    const float* const Wc0 = W1 + c0;

    float acc[8][4];
    #pragma unroll
    for (int i = 0; i < 8; ++i)
        #pragma unroll
        for (int j = 0; j < 4; ++j) acc[i][j] = 0.f;

    float4 wA[4], wB[4];

    // ---- prologue: W for k-chunk 0 into set A ----
    #pragma unroll
    for (int kk = 0; kk < 4; ++kk)
        wA[kk] = *(const float4*)(Wc0 + (kk << 7));

#define SA_PREFETCH_W(WW, KC)                                             \
    {                                                                     \
        const int kb_ = (KC) << 2;                                        \
        _Pragma("unroll")                                                 \
        for (int kk = 0; kk < 4; ++kk)                                    \
            WW[kk] = *(const float4*)(Wc0 + ((kb_ + kk) << 7));           \
    }

#define SA_COMPUTE(WW, KC)                                                \
    {                                                                     \
        const int kc_ = (KC);                                             \
        float4 fr[8];                                                     \
        _Pragma("unroll")                                                 \
        for (int i = 0; i < 8; ++i) {                                     \
            const int row = r0 + i;                                       \
            fr[i] = fsmv[row * 32 + (kc_ ^ (row & 31))];                  \
        }                                                                 \
        const float* frp = (const float*)fr;                              \
        const float* wp  = (const float*)WW;                              \
        _Pragma("unroll")                                                 \
        for (int kk = 0; kk < 4; ++kk)                                    \
            _Pragma("unroll")                                             \
            for (int ri = 0; ri < 8; ++ri) {                              \
                const float f = frp[ri * 4 + kk];                         \
                _Pragma("unroll")                                         \
                for (int ci = 0; ci < 4; ++ci)                            \
                    acc[ri][ci] = fmaf(f, wp[kk * 4 + ci], acc[ri][ci]);  \
            }                                                             \
    }

    for (int kc = 0; kc < 32; kc += 2) {
        SA_PREFETCH_W(wB, kc + 1)               // kc+1 <= 31 always
        SA_COMPUTE(wA, kc)                      // chunk kc (fr inline)
        SA_PREFETCH_W(wA, (kc + 2) & 31)        // last iter reloads 0 (unused)
        SA_COMPUTE(wB, kc + 1)                  // chunk kc+1
    }
#undef SA_PREFETCH_W
#undef SA_COMPUTE

    __syncthreads(); // all fsm reads done before overwrite with act

    // BN (eval) + ReLU  (identical formulas/order per (row,col))
    #pragma unroll
    for (int ci = 0; ci < 4; ++ci) {
        const int c = c0 + ci;
        const float inv = bng[c] / sqrtf(bnv[c] + BNEPS);
        const float mu = bnm[c];
        const float be = bnb[c];
        const float bb = b1[c];
        #pragma unroll
        for (int ri = 0; ri < 8; ++ri) {
            const float h = (acc[ri][ci] + bb - mu) * inv + be;
            acc[ri][ci] = fmaxf(h, 0.f);
        }
    }
    // act tile -> LDS in the SAME swizzled float4 layout (g = tid&31)
    {
        const int g = tid & 31;
        #pragma unroll
        for (int ri = 0; ri < 8; ++ri) {
            const int row = r0 + ri;
            float4 av;
            av.x = acc[ri][0]; av.y = acc[ri][1];
            av.z = acc[ri][2]; av.w = acc[ri][3];
            fsmv[row * 32 + (g ^ (row & 31))] = av;
        }
    }
    __syncthreads();

    // GEMM2: logits[r][o] = sum_c act[r][c] * W2[c][o]; c ascending
    // (group-major float4 reads preserve the exact per-(r,o) fmaf chain).
    const int r = tid & 63;
    const int ogrp = tid >> 6;  // wave-uniform
    float lg[3] = {0.f, 0.f, 0.f};
    for (int g = 0; g < 32; ++g) {
        const float4 av = fsmv[r * 32 + (g ^ (r & 31))];
        const float a4[4] = {av.x, av.y, av.z, av.w};
        #pragma unroll
        for (int cc = 0; cc < 4; ++cc) {
            const int c = (g << 2) + cc;
            const float a = a4[cc];
            #pragma unroll
            for (int i = 0; i < 3; ++i) {
                const int o = ogrp + 4 * i;
                if (o < NCLS) lg[i] = fmaf(a, W2hm[c * NCLS + o], lg[i]);
            }
        }
    }
    const int n = gbase + r;
    const int b = n >> 15;          // NV = 2^15
    const int v = n & (NV - 1);
    unsigned int* sb = scoreb + (size_t)b * NK;
    #pragma unroll
    for (int i = 0; i < 3; ++i) {
        const int o = ogrp + 4 * i;
        if (o < NCLS) {
            const float x = lg[i] + b2hm[o];
            const float s = 1.f / (1.f + expf(-x));
            sb[o * NV + v] = __float_as_uint(s);
        }
    }
}

// ---------------------------------------------------------------------------
// Stage B1: per-chunk PARTIAL 20-bit histograms, plain stores (no global
// atomics, no zeroing kernel). grid (NP, B) = 128 blocks.
// ---------------------------------------------------------------------------
__global__ __launch_bounds__(256) void stageB1_kernel(
    const unsigned int* __restrict__ scoreb,
    unsigned int* __restrict__ hist_part)
{
    __shared__ unsigned int lh[H20BINS];
    const int tid = threadIdx.x;
    const int b = blockIdx.y;
    const uint4* sb4 = (const uint4*)(scoreb + (size_t)b * NK) + (size_t)blockIdx.x * PCHUNK4;

    for (int i = tid; i < H20BINS; i += 256) lh[i] = 0u;
    __syncthreads();

    #pragma unroll
    for (int q = 0; q < 10; ++q) {                // 10*256 = 2560 uint4
        const uint4 v = sb4[q * 256 + tid];
        const unsigned int sv[4] = {v.x, v.y, v.z, v.w};
        #pragma unroll
        for (int k = 0; k < 4; ++k) {
            const int rel = (int)(sv[k] >> 12) - H20CUT;
            if (rel >= 0) atomicAdd(&lh[rel], 1u);
        }
    }
    __syncthreads();

    unsigned int* gh = hist_part + ((size_t)b * NP + blockIdx.x) * H20BINS;
    for (int i = tid; i < H20BINS; i += 256) gh[i] = lh[i];   // ALL bins
}

// ---------------------------------------------------------------------------
// Stage B2: sum partials + suffix-scan -> threshold T (20-bit truncated).
// grid (B), 1024 thr. Also zeroes cnt[b]. Deterministic (fixed sum order).
// ---------------------------------------------------------------------------
__global__ __launch_bounds__(1024) void stageB2_kernel(
    const unsigned int* __restrict__ hist_part,
    unsigned int* __restrict__ Tbuf,
    unsigned int* __restrict__ cnt)
{
    __shared__ unsigned int part[1024];
    __shared__ unsigned int sT;
    const int b = blockIdx.x;
    const int tid = threadIdx.x;  // owns bins [tid*6, tid*6+6)

    unsigned int loc[6] = {0u, 0u, 0u, 0u, 0u, 0u};
    const unsigned int* hp = hist_part + (size_t)b * NP * H20BINS;
    for (int p = 0; p < NP; ++p) {
        const unsigned int* hq = hp + (size_t)p * H20BINS + tid * 6;
        #pragma unroll
        for (int i = 0; i < 6; ++i) loc[i] += hq[i];
    }
    unsigned int Ls = 0;
    #pragma unroll
    for (int i = 0; i < 6; ++i) Ls += loc[i];
    part[tid] = Ls;
    __syncthreads();

    // inclusive suffix scan over 1024 partials (Hillis-Steele, 10 steps)
    for (int off = 1; off < 1024; off <<= 1) {
        const unsigned int add = (tid + off < 1024) ? part[tid + off] : 0u;
        __syncthreads();
        part[tid] += add;
        __syncthreads();
    }
    const unsigned int incl = part[tid];          // sum of segments >= tid
    const unsigned int above_seg = incl - Ls;     // sum of segments  > tid

    if (above_seg < KSEL && incl >= KSEL) {       // exactly one thread
        int above = (int)above_seg;
        int tbin = -1;
        #pragma unroll
        for (int i = 5; i >= 0; --i) {
            const int cbin = (int)loc[i];
            if (tbin < 0) {
                if (above + cbin >= KSEL) tbin = tid * 6 + i;
                else above += cbin;
            }
        }
        sT = ((unsigned int)(tbin + H20CUT)) << 12;
    }
    if (tid == 0 && part[0] < KSEL) sT = ((unsigned int)H20CUT) << 12;  // degenerate
    __syncthreads();
    if (tid == 0) {
        Tbuf[b] = sT;
        cnt[b] = 0u;
    }
}

// ---------------------------------------------------------------------------
// Stage B3: filter s >= T, per-block LDS aggregation -> ONE global atomic
// per block. grid (NP, B) = 128 blocks.
// ---------------------------------------------------------------------------
__global__ __launch_bounds__(256) void stageB3_kernel(
    const unsigned int* __restrict__ scoreb,
    const unsigned int* __restrict__ Tbuf,
    unsigned int* __restrict__ cnt,
    unsigned long long* __restrict__ cand)
{
    __shared__ unsigned long long lbuf[LCAP];
    __shared__ unsigned int lcnt;
    __shared__ unsigned int sbase;
    const int tid = threadIdx.x;
    const int b = blockIdx.y;
    const unsigned int T = Tbuf[b];
    const uint4* sb4 = (const uint4*)(scoreb + (size_t)b * NK) + (size_t)blockIdx.x * PCHUNK4;
    unsigned long long* cb = cand + (size_t)b * CANDCAP;

    if (tid == 0) lcnt = 0u;
    __syncthreads();

    #pragma unroll
    for (int q = 0; q < 10; ++q) {
        const int vi = q * 256 + tid;
        const uint4 v = sb4[vi];
        const unsigned int sv[4] = {v.x, v.y, v.z, v.w};
        const unsigned int i0 = (unsigned int)((blockIdx.x * PCHUNK4 + vi) * 4);
        #pragma unroll
        for (int k = 0; k < 4; ++k) {
            if (sv[k] >= T) {
                const unsigned long long key =
                    ((unsigned long long)sv[k] << 32) |
                    (unsigned long long)(0xFFFFFFFFu - (i0 + k));
                const unsigned int p = atomicAdd(&lcnt, 1u);
                if (p < LCAP) {
                    lbuf[p] = key;
                } else {                           // overflow: direct global
                    const unsigned int gp = atomicAdd(&cnt[b], 1u);
                    if (gp < CANDCAP) cb[gp] = key;
                }
            }
        }
    }
    __syncthreads();
    const unsigned int nloc = min(lcnt, (unsigned int)LCAP);
    if (tid == 0) sbase = (nloc > 0u) ? atomicAdd(&cnt[b], nloc) : 0u;
    __syncthreads();
    const unsigned int base = sbase;
    for (unsigned int i = tid; i < nloc; i += 256) {
        const unsigned int pos = base + i;
        if (pos < CANDCAP) cb[pos] = lbuf[i];
    }
}

// ---------------------------------------------------------------------------
// Stage B4: bitonic sort candidates desc (sized to count), emit top-500.
// grid (B), 1024 thr.
// ---------------------------------------------------------------------------
__global__ __launch_bounds__(1024) void stageB4_kernel(
    const unsigned long long* __restrict__ cand,
    const unsigned int* __restrict__ cnt,
    float* __restrict__ sel_score,
    int* __restrict__ sel_cls,
    int* __restrict__ sel_vox)
{
    __shared__ unsigned long long kbuf[CANDCAP];
    const int b = blockIdx.x;
    const int tid = threadIdx.x;
    const int n = min((int)cnt[b], CANDCAP);
    int m = 512;
    while (m < n) m <<= 1;
    for (int i = tid; i < m; i += 1024)
        kbuf[i] = (i < n) ? cand[(size_t)b * CANDCAP + i] : 0ull;
    __syncthreads();
    for (int size = 2; size <= m; size <<= 1) {
        for (int stride = size >> 1; stride > 0; stride >>= 1) {
            for (int j = tid; j < m; j += 1024) {
                const int p = j ^ stride;
                if (p > j) {
                    const unsigned long long x = kbuf[j];
                    const unsigned long long y = kbuf[p];
                    const bool descRegion = ((j & size) == 0);
                    if ((x < y) == descRegion) { kbuf[j] = y; kbuf[p] = x; }
                }
            }
            __syncthreads();
        }
    }
    if (tid < KSEL) {
        const unsigned long long kk = kbuf[tid];
        const unsigned int s32 = (unsigned int)(kk >> 32);
        const unsigned int fl = 0xFFFFFFFFu - (unsigned int)(kk & 0xFFFFFFFFull);
        const int idx = b * KSEL + tid;
        sel_score[idx] = __uint_as_float(s32);
        sel_cls[idx] = (int)(fl >> 15);
        sel_vox[idx] = (int)(fl & (NV - 1));
    }
}

// ---------------------------------------------------------------------------
// Stage C+D fused, head-parallel: 640 threads = 5 heads x 128 cols; all 5
// head-GEMMs run concurrently. GEMM2 = 40 parallel 128-dots. Per-(row,col)
// k/cc order identical to the verified version -> bitwise identical.
// ---------------------------------------------------------------------------
__global__ __launch_bounds__(640) void stageCD_kernel(
    const float* __restrict__ feats,
    const int* __restrict__ voxel_xy,
    const float* __restrict__ sel_score,
    const int* __restrict__ sel_cls,
    const int* __restrict__ sel_vox,
    const float* __restrict__ W1,
    const float* __restrict__ b1,
    const float* __restrict__ bng,
    const float* __restrict__ bnb,
    const float* __restrict__ bnm,
    const float* __restrict__ bnv,
    const float* __restrict__ W2c, const float* __restrict__ b2c,
    const float* __restrict__ W2z, const float* __restrict__ b2z,
    const float* __restrict__ W2d, const float* __restrict__ b2d,
    const float* __restrict__ W2r, const float* __restrict__ b2r,
    const float* __restrict__ W2v, const float* __restrict__ b2v,
    float* __restrict__ out,
    int total)
{
    __shared__ float fs[4][128];
    __shared__ float as_[5][4][128];
    __shared__ float dec_s[4][10];
    __shared__ int vsel[4];
    const int tid = threadIdx.x;
    const int s0 = blockIdx.x * 4;

    if (tid < 4) {
        const int s = s0 + tid;
        vsel[tid] = (s / KSEL) * NV + sel_vox[s];
    }
    __syncthreads();
    if (tid < 512) {
        const int j = tid >> 7;
        const int c = tid & 127;
        fs[j][c] = feats[((size_t)vsel[j] << 7) + c];
    }
    __syncthreads();

    // ---- GEMM1 + BN + ReLU, all 5 heads concurrent ----
    {
        const int h = tid / 128;       // 0..4 (wave-uniform: 128 = 2 waves)
        const int c = tid & 127;
        const int head = h + 1;
        float acc[4] = {0.f, 0.f, 0.f, 0.f};
        const float* Wh = W1 + head * (CD * CD) + c;
        for (int k = 0; k < 128; ++k) {
            const float w = Wh[k << 7];
            #pragma unroll
            for (int j = 0; j < 4; ++j)
                acc[j] = fmaf(fs[j][k], w, acc[j]);
        }
        const int hc = head * CD + c;
        const float inv = bng[hc] / sqrtf(bnv[hc] + BNEPS);
        const float mu = bnm[hc], be = bnb[hc], bb = b1[hc];
        #pragma unroll
        for (int j = 0; j < 4; ++j) {
            const float hv = (acc[j] + bb - mu) * inv + be;
            as_[h][j][c] = fmaxf(hv, 0.f);
        }
    }
    __syncthreads();

    // ---- GEMM2: 40 independent 128-dots (row j, output slot) ----
    if (tid < 40) {
        const int j = tid / 10;
        const int slot = tid % 10;
        const float* w2; const float* bb2; int hh, o, oc; bool ex = false;
        if (slot < 2)      { w2 = W2c; bb2 = b2c; hh = 0; o = slot;     oc = 2; }
        else if (slot < 3) { w2 = W2z; bb2 = b2z; hh = 1; o = 0;        oc = 1; }
        else if (slot < 6) { w2 = W2d; bb2 = b2d; hh = 2; o = slot - 3; oc = 3; ex = true; }
        else if (slot < 8) { w2 = W2r; bb2 = b2r; hh = 3; o = slot - 6; oc = 2; }
        else               { w2 = W2v; bb2 = b2v; hh = 4; o = slot - 8; oc = 2; }
        float a = 0.f;
        for (int cc = 0; cc < 128; ++cc)
            a = fmaf(as_[hh][j][cc], w2[cc * oc + o], a);
        a += bb2[o];
        if (ex) a = expf(a);
        dec_s[j][slot] = a;
    }
    __syncthreads();

    // ---- decode (stageD formulas, bitwise identical) ----
    if (tid < 4) {
        const int s = s0 + tid;
        const int b = s / KSEL;
        const float score = sel_score[s];
        const int cls = sel_cls[s];
        const int v = sel_vox[s];
        const int n = b * NV + v;
        const float xi = (float)voxel_xy[2 * n];
        const float yi = (float)voxel_xy[2 * n + 1];
        const float* dd = dec_s[tid];
        const float cx = dd[0], cy = dd[1], cz = dd[2];
        const float d0 = dd[3], d1 = dd[4], d2 = dd[5];
        const float rc = dd[6], rs = dd[7], ve0 = dd[8], ve1 = dd[9];
        const float SV = 0.075f * 8.0f;
        const float xs = (xi + cx) * SV + (-54.0f);
        const float ys = (yi + cy) * SV + (-54.0f);
        const float ang = atan2f(rs, rc);
        const bool mk = (xs >= -61.2f) && (ys >= -61.2f) && (cz >= -10.0f) &&
                        (xs <= 61.2f) && (ys <= 61.2f) && (cz <= 10.0f) &&
                        (score > 0.1f);
        const float m = mk ? 1.f : 0.f;
        float* bx = out + (size_t)s * 10;
        bx[0] = xs * m; bx[1] = ys * m; bx[2] = cz * m;
        bx[3] = d0 * m; bx[4] = d1 * m; bx[5] = d2 * m;
        bx[6] = ang * m; bx[7] = ve0 * m; bx[8] = ve1 * m; bx[9] = score * m;
        out[(size_t)total * 10 + s] = mk ? (float)(cls + 1) : 0.f;
        out[(size_t)total * 11 + s] = (float)n;
        out[(size_t)total * 12 + s] = m;
    }
}

extern "C" void kernel_launch(void* const* d_in, const int* in_sizes, int n_in,
                              void* d_out, int out_size, void* d_ws, size_t ws_size,
                              hipStream_t stream) {
    const float* feats   = (const float*)d_in[0];
    const int*   voxelxy = (const int*)d_in[1];
    const float* W1   = (const float*)d_in[2];
    const float* b1   = (const float*)d_in[3];
    const float* bng  = (const float*)d_in[4];
    const float* bnb  = (const float*)d_in[5];
    const float* bnm  = (const float*)d_in[6];
    const float* bnv  = (const float*)d_in[7];
    const float* W2hm = (const float*)d_in[8];
    const float* b2hm = (const float*)d_in[9];
    const float* W2c  = (const float*)d_in[10];
    const float* b2c  = (const float*)d_in[11];
    const float* W2z  = (const float*)d_in[12];
    const float* b2z  = (const float*)d_in[13];
    const float* W2d  = (const float*)d_in[14];
    const float* b2d  = (const float*)d_in[15];
    const float* W2r  = (const float*)d_in[16];
    const float* b2r  = (const float*)d_in[17];
    const float* W2v  = (const float*)d_in[18];
    const float* b2v  = (const float*)d_in[19];

    const int B = in_sizes[0] / (NV * CD);
    const int N = B * NV;
    const int total = B * KSEL;

    // workspace layout (8-byte aligned blocks)
    char* ws = (char*)d_ws;
    unsigned int* scoreb    = (unsigned int*)ws;         ws += (size_t)B * NK * 4;
    unsigned int* hist_part = (unsigned int*)ws;         ws += (size_t)B * NP * H20BINS * 4;
    unsigned int* cnt       = (unsigned int*)ws;         ws += 8 * 4;
    unsigned int* Tbuf      = (unsigned int*)ws;         ws += 8 * 4;
    unsigned long long* cand = (unsigned long long*)ws;  ws += (size_t)B * CANDCAP * 8;
    float* sel_score = (float*)ws;                       ws += (size_t)total * 4;
    int*   sel_cls   = (int*)ws;                         ws += (size_t)total * 4;
    int*   sel_vox   = (int*)ws;                         ws += (size_t)total * 4;

    stageA_kernel<<<dim3(N / 64), dim3(256), 0, stream>>>(
        feats, W1, b1, bng, bnb, bnm, bnv, W2hm, b2hm, scoreb);

    stageB1_kernel<<<dim3(NP, B), dim3(256), 0, stream>>>(scoreb, hist_part);
    stageB2_kernel<<<dim3(B), dim3(1024), 0, stream>>>(hist_part, Tbuf, cnt);
    stageB3_kernel<<<dim3(NP, B), dim3(256), 0, stream>>>(scoreb, Tbuf, cnt, cand);
    stageB4_kernel<<<dim3(B), dim3(1024), 0, stream>>>(
        cand, cnt, sel_score, sel_cls, sel_vox);

    stageCD_kernel<<<dim3(total / 4), dim3(640), 0, stream>>>(
        feats, voxelxy, sel_score, sel_cls, sel_vox,
        W1, b1, bng, bnb, bnm, bnv,
        W2c, b2c, W2z, b2z, W2d, b2d, W2r, b2r, W2v, b2v,
        (float*)d_out, total);
}

// Round 15
// 262.656 us; speedup vs baseline: 1.2353x; 1.1080x over previous
//
#include <hip/hip_runtime.h>
#include <math.h>

#define NV 32768
#define CD 128
#define NCLS 10
#define KSEL 500
#define BNEPS 1e-5f
#define NK (NCLS * NV)          // 327680 keys per batch
#define H20CUT 0x3E000          // (s>>12) floor for score >= 0.125
#define H20BINS 6144            // (0x3F800 - 0x3E000); sigmoid < 1.0
#define CANDCAP 2048
#define NP 32                   // histogram/filter chunks per batch
#define PCHUNKV (NK / NP)       // 10240 keys per chunk
#define PCHUNK4 (PCHUNKV / 4)   // 2560 uint4 per chunk
#define LCAP 512                // per-block LDS candidate list capacity

// ---------------------------------------------------------------------------
// Stage A: hm head over all voxels. 64 rows x 128 cols per block (256 thr),
// 2048 blocks, 8 rows x 4 cols per thread. Recombination of the two proven
// winners: r12's structure (W register double-buffer, w2s/b2s in LDS for
// GEMM2 broadcast reads — r14 showed W2-from-global costs ~40 µs) + r14's
// float4 swizzled act layout (bank conflicts 917K -> 0, vectorized act
// store + float4 GEMM2 act reads). LDS ~37.9 KB -> 4 blocks/CU, same
// register regime as r12 (no spill). fmaf order per (row,col) k-ascending
// and GEMM2 per-(r,o) c-ascending on identical values -> bitwise identical.
// ---------------------------------------------------------------------------
__global__ __launch_bounds__(256, 4) void stageA_kernel(
    const float* __restrict__ feats,
    const float* __restrict__ W1,
    const float* __restrict__ b1,
    const float* __restrict__ bng,
    const float* __restrict__ bnb,
    const float* __restrict__ bnm,
    const float* __restrict__ bnv,
    const float* __restrict__ W2hm,
    const float* __restrict__ b2hm,
    unsigned int* __restrict__ scoreb)
{
    // 32 KB union: swizzled feats (8192 floats) / swizzled act (8192 floats)
    __shared__ __align__(16) float smem[64 * 128];
    __shared__ float w2s[CD * NCLS];
    __shared__ float b2s[NCLS];
    float4* const fsmv = (float4*)smem;

    const int tid = threadIdx.x;
    const int gbase = blockIdx.x * 64;

    for (int i = tid; i < CD * NCLS; i += 256) w2s[i] = W2hm[i];
    if (tid < NCLS) b2s[tid] = b2hm[tid];

    // feats tile -> LDS, swizzled: (r, float4-group g) at fsmv[r*32 + (g^(r&31))]
    for (int t = tid; t < 64 * 32; t += 256) {
        const int r = t >> 5;
        const int g = t & 31;
        const float4 v = *(const float4*)(feats + (((size_t)(gbase + r)) << 7) + (g << 2));
        fsmv[r * 32 + (g ^ (r & 31))] = v;
    }
    __syncthreads();

    const int c0 = (tid & 31) << 2;   // 4 output cols (32 col groups)
    const int r0 = (tid >> 5) << 3;   // 8 rows (8 row groups -> 64 rows)
    const float* const Wc0 = W1 + c0;

    float acc[8][4];
    #pragma unroll
    for (int i = 0; i < 8; ++i)
        #pragma unroll
        for (int j = 0; j < 4; ++j) acc[i][j] = 0.f;

    float4 wA[4], wB[4];

    // ---- prologue: W for k-chunk 0 into set A ----
    #pragma unroll
    for (int kk = 0; kk < 4; ++kk)
        wA[kk] = *(const float4*)(Wc0 + (kk << 7));

#define SA_PREFETCH_W(WW, KC)                                             \
    {                                                                     \
        const int kb_ = (KC) << 2;                                        \
        _Pragma("unroll")                                                 \
        for (int kk = 0; kk < 4; ++kk)                                    \
            WW[kk] = *(const float4*)(Wc0 + ((kb_ + kk) << 7));           \
    }

#define SA_COMPUTE(WW, KC)                                                \
    {                                                                     \
        const int kc_ = (KC);                                             \
        float4 fr[8];                                                     \
        _Pragma("unroll")                                                 \
        for (int i = 0; i < 8; ++i) {                                     \
            const int row = r0 + i;                                       \
            fr[i] = fsmv[row * 32 + (kc_ ^ (row & 31))];                  \
        }                                                                 \
        const float* frp = (const float*)fr;                              \
        const float* wp  = (const float*)WW;                              \
        _Pragma("unroll")                                                 \
        for (int kk = 0; kk < 4; ++kk)                                    \
            _Pragma("unroll")                                             \
            for (int ri = 0; ri < 8; ++ri) {                              \
                const float f = frp[ri * 4 + kk];                         \
                _Pragma("unroll")                                         \
                for (int ci = 0; ci < 4; ++ci)                            \
                    acc[ri][ci] = fmaf(f, wp[kk * 4 + ci], acc[ri][ci]);  \
            }                                                             \
    }

    for (int kc = 0; kc < 32; kc += 2) {
        SA_PREFETCH_W(wB, kc + 1)               // kc+1 <= 31 always
        SA_COMPUTE(wA, kc)                      // chunk kc (fr inline)
        SA_PREFETCH_W(wA, (kc + 2) & 31)        // last iter reloads 0 (unused)
        SA_COMPUTE(wB, kc + 1)                  // chunk kc+1
    }
#undef SA_PREFETCH_W
#undef SA_COMPUTE

    __syncthreads(); // all fsm reads done before overwrite with act

    // BN (eval) + ReLU  (identical formulas/order per (row,col))
    #pragma unroll
    for (int ci = 0; ci < 4; ++ci) {
        const int c = c0 + ci;
        const float inv = bng[c] / sqrtf(bnv[c] + BNEPS);
        const float mu = bnm[c];
        const float be = bnb[c];
        const float bb = b1[c];
        #pragma unroll
        for (int ri = 0; ri < 8; ++ri) {
            const float h = (acc[ri][ci] + bb - mu) * inv + be;
            acc[ri][ci] = fmaxf(h, 0.f);
        }
    }
    // act tile -> LDS in the SAME swizzled float4 layout (g = tid&31)
    {
        const int g = tid & 31;
        #pragma unroll
        for (int ri = 0; ri < 8; ++ri) {
            const int row = r0 + ri;
            float4 av;
            av.x = acc[ri][0]; av.y = acc[ri][1];
            av.z = acc[ri][2]; av.w = acc[ri][3];
            fsmv[row * 32 + (g ^ (row & 31))] = av;
        }
    }
    __syncthreads();

    // GEMM2: logits[r][o] = sum_c act[r][c] * W2[c][o]; c ascending via
    // group-major float4 act reads + LDS-broadcast w2s (r12's fast path).
    const int r = tid & 63;
    const int ogrp = tid >> 6;  // wave-uniform
    float lg[3] = {0.f, 0.f, 0.f};
    for (int g = 0; g < 32; ++g) {
        const float4 av = fsmv[r * 32 + (g ^ (r & 31))];
        const float a4[4] = {av.x, av.y, av.z, av.w};
        #pragma unroll
        for (int cc = 0; cc < 4; ++cc) {
            const int c = (g << 2) + cc;
            const float a = a4[cc];
            #pragma unroll
            for (int i = 0; i < 3; ++i) {
                const int o = ogrp + 4 * i;
                if (o < NCLS) lg[i] = fmaf(a, w2s[c * NCLS + o], lg[i]);
            }
        }
    }
    const int n = gbase + r;
    const int b = n >> 15;          // NV = 2^15
    const int v = n & (NV - 1);
    unsigned int* sb = scoreb + (size_t)b * NK;
    #pragma unroll
    for (int i = 0; i < 3; ++i) {
        const int o = ogrp + 4 * i;
        if (o < NCLS) {
            const float x = lg[i] + b2s[o];
            const float s = 1.f / (1.f + expf(-x));
            sb[o * NV + v] = __float_as_uint(s);
        }
    }
}

// ---------------------------------------------------------------------------
// Stage B1: per-chunk PARTIAL 20-bit histograms, plain stores (no global
// atomics, no zeroing kernel). grid (NP, B) = 128 blocks.
// ---------------------------------------------------------------------------
__global__ __launch_bounds__(256) void stageB1_kernel(
    const unsigned int* __restrict__ scoreb,
    unsigned int* __restrict__ hist_part)
{
    __shared__ unsigned int lh[H20BINS];
    const int tid = threadIdx.x;
    const int b = blockIdx.y;
    const uint4* sb4 = (const uint4*)(scoreb + (size_t)b * NK) + (size_t)blockIdx.x * PCHUNK4;

    for (int i = tid; i < H20BINS; i += 256) lh[i] = 0u;
    __syncthreads();

    #pragma unroll
    for (int q = 0; q < 10; ++q) {                // 10*256 = 2560 uint4
        const uint4 v = sb4[q * 256 + tid];
        const unsigned int sv[4] = {v.x, v.y, v.z, v.w};
        #pragma unroll
        for (int k = 0; k < 4; ++k) {
            const int rel = (int)(sv[k] >> 12) - H20CUT;
            if (rel >= 0) atomicAdd(&lh[rel], 1u);
        }
    }
    __syncthreads();

    unsigned int* gh = hist_part + ((size_t)b * NP + blockIdx.x) * H20BINS;
    for (int i = tid; i < H20BINS; i += 256) gh[i] = lh[i];   // ALL bins
}

// ---------------------------------------------------------------------------
// Stage B2: sum partials + suffix-scan -> threshold T (20-bit truncated).
// grid (B), 1024 thr. Also zeroes cnt[b]. Deterministic (fixed sum order).
// ---------------------------------------------------------------------------
__global__ __launch_bounds__(1024) void stageB2_kernel(
    const unsigned int* __restrict__ hist_part,
    unsigned int* __restrict__ Tbuf,
    unsigned int* __restrict__ cnt)
{
    __shared__ unsigned int part[1024];
    __shared__ unsigned int sT;
    const int b = blockIdx.x;
    const int tid = threadIdx.x;  // owns bins [tid*6, tid*6+6)

    unsigned int loc[6] = {0u, 0u, 0u, 0u, 0u, 0u};
    const unsigned int* hp = hist_part + (size_t)b * NP * H20BINS;
    for (int p = 0; p < NP; ++p) {
        const unsigned int* hq = hp + (size_t)p * H20BINS + tid * 6;
        #pragma unroll
        for (int i = 0; i < 6; ++i) loc[i] += hq[i];
    }
    unsigned int Ls = 0;
    #pragma unroll
    for (int i = 0; i < 6; ++i) Ls += loc[i];
    part[tid] = Ls;
    __syncthreads();

    // inclusive suffix scan over 1024 partials (Hillis-Steele, 10 steps)
    for (int off = 1; off < 1024; off <<= 1) {
        const unsigned int add = (tid + off < 1024) ? part[tid + off] : 0u;
        __syncthreads();
        part[tid] += add;
        __syncthreads();
    }
    const unsigned int incl = part[tid];          // sum of segments >= tid
    const unsigned int above_seg = incl - Ls;     // sum of segments  > tid

    if (above_seg < KSEL && incl >= KSEL) {       // exactly one thread
        int above = (int)above_seg;
        int tbin = -1;
        #pragma unroll
        for (int i = 5; i >= 0; --i) {
            const int cbin = (int)loc[i];
            if (tbin < 0) {
                if (above + cbin >= KSEL) tbin = tid * 6 + i;
                else above += cbin;
            }
        }
        sT = ((unsigned int)(tbin + H20CUT)) << 12;
    }
    if (tid == 0 && part[0] < KSEL) sT = ((unsigned int)H20CUT) << 12;  // degenerate
    __syncthreads();
    if (tid == 0) {
        Tbuf[b] = sT;
        cnt[b] = 0u;
    }
}

// ---------------------------------------------------------------------------
// Stage B3: filter s >= T, per-block LDS aggregation -> ONE global atomic
// per block. grid (NP, B) = 128 blocks.
// ---------------------------------------------------------------------------
__global__ __launch_bounds__(256) void stageB3_kernel(
    const unsigned int* __restrict__ scoreb,
    const unsigned int* __restrict__ Tbuf,
    unsigned int* __restrict__ cnt,
    unsigned long long* __restrict__ cand)
{
    __shared__ unsigned long long lbuf[LCAP];
    __shared__ unsigned int lcnt;
    __shared__ unsigned int sbase;
    const int tid = threadIdx.x;
    const int b = blockIdx.y;
    const unsigned int T = Tbuf[b];
    const uint4* sb4 = (const uint4*)(scoreb + (size_t)b * NK) + (size_t)blockIdx.x * PCHUNK4;
    unsigned long long* cb = cand + (size_t)b * CANDCAP;

    if (tid == 0) lcnt = 0u;
    __syncthreads();

    #pragma unroll
    for (int q = 0; q < 10; ++q) {
        const int vi = q * 256 + tid;
        const uint4 v = sb4[vi];
        const unsigned int sv[4] = {v.x, v.y, v.z, v.w};
        const unsigned int i0 = (unsigned int)((blockIdx.x * PCHUNK4 + vi) * 4);
        #pragma unroll
        for (int k = 0; k < 4; ++k) {
            if (sv[k] >= T) {
                const unsigned long long key =
                    ((unsigned long long)sv[k] << 32) |
                    (unsigned long long)(0xFFFFFFFFu - (i0 + k));
                const unsigned int p = atomicAdd(&lcnt, 1u);
                if (p < LCAP) {
                    lbuf[p] = key;
                } else {                           // overflow: direct global
                    const unsigned int gp = atomicAdd(&cnt[b], 1u);
                    if (gp < CANDCAP) cb[gp] = key;
                }
            }
        }
    }
    __syncthreads();
    const unsigned int nloc = min(lcnt, (unsigned int)LCAP);
    if (tid == 0) sbase = (nloc > 0u) ? atomicAdd(&cnt[b], nloc) : 0u;
    __syncthreads();
    const unsigned int base = sbase;
    for (unsigned int i = tid; i < nloc; i += 256) {
        const unsigned int pos = base + i;
        if (pos < CANDCAP) cb[pos] = lbuf[i];
    }
}

// ---------------------------------------------------------------------------
// Stage B4: bitonic sort candidates desc (sized to count), emit top-500.
// grid (B), 1024 thr.
// ---------------------------------------------------------------------------
__global__ __launch_bounds__(1024) void stageB4_kernel(
    const unsigned long long* __restrict__ cand,
    const unsigned int* __restrict__ cnt,
    float* __restrict__ sel_score,
    int* __restrict__ sel_cls,
    int* __restrict__ sel_vox)
{
    __shared__ unsigned long long kbuf[CANDCAP];
    const int b = blockIdx.x;
    const int tid = threadIdx.x;
    const int n = min((int)cnt[b], CANDCAP);
    int m = 512;
    while (m < n) m <<= 1;
    for (int i = tid; i < m; i += 1024)
        kbuf[i] = (i < n) ? cand[(size_t)b * CANDCAP + i] : 0ull;
    __syncthreads();
    for (int size = 2; size <= m; size <<= 1) {
        for (int stride = size >> 1; stride > 0; stride >>= 1) {
            for (int j = tid; j < m; j += 1024) {
                const int p = j ^ stride;
                if (p > j) {
                    const unsigned long long x = kbuf[j];
                    const unsigned long long y = kbuf[p];
                    const bool descRegion = ((j & size) == 0);
                    if ((x < y) == descRegion) { kbuf[j] = y; kbuf[p] = x; }
                }
            }
            __syncthreads();
        }
    }
    if (tid < KSEL) {
        const unsigned long long kk = kbuf[tid];
        const unsigned int s32 = (unsigned int)(kk >> 32);
        const unsigned int fl = 0xFFFFFFFFu - (unsigned int)(kk & 0xFFFFFFFFull);
        const int idx = b * KSEL + tid;
        sel_score[idx] = __uint_as_float(s32);
        sel_cls[idx] = (int)(fl >> 15);
        sel_vox[idx] = (int)(fl & (NV - 1));
    }
}

// ---------------------------------------------------------------------------
// Stage C+D fused, head-parallel: 640 threads = 5 heads x 128 cols; all 5
// head-GEMMs run concurrently. GEMM2 = 40 parallel 128-dots. Per-(row,col)
// k/cc order identical to the verified version -> bitwise identical.
// ---------------------------------------------------------------------------
__global__ __launch_bounds__(640) void stageCD_kernel(
    const float* __restrict__ feats,
    const int* __restrict__ voxel_xy,
    const float* __restrict__ sel_score,
    const int* __restrict__ sel_cls,
    const int* __restrict__ sel_vox,
    const float* __restrict__ W1,
    const float* __restrict__ b1,
    const float* __restrict__ bng,
    const float* __restrict__ bnb,
    const float* __restrict__ bnm,
    const float* __restrict__ bnv,
    const float* __restrict__ W2c, const float* __restrict__ b2c,
    const float* __restrict__ W2z, const float* __restrict__ b2z,
    const float* __restrict__ W2d, const float* __restrict__ b2d,
    const float* __restrict__ W2r, const float* __restrict__ b2r,
    const float* __restrict__ W2v, const float* __restrict__ b2v,
    float* __restrict__ out,
    int total)
{
    __shared__ float fs[4][128];
    __shared__ float as_[5][4][128];
    __shared__ float dec_s[4][10];
    __shared__ int vsel[4];
    const int tid = threadIdx.x;
    const int s0 = blockIdx.x * 4;

    if (tid < 4) {
        const int s = s0 + tid;
        vsel[tid] = (s / KSEL) * NV + sel_vox[s];
    }
    __syncthreads();
    if (tid < 512) {
        const int j = tid >> 7;
        const int c = tid & 127;
        fs[j][c] = feats[((size_t)vsel[j] << 7) + c];
    }
    __syncthreads();

    // ---- GEMM1 + BN + ReLU, all 5 heads concurrent ----
    {
        const int h = tid / 128;       // 0..4 (wave-uniform: 128 = 2 waves)
        const int c = tid & 127;
        const int head = h + 1;
        float acc[4] = {0.f, 0.f, 0.f, 0.f};
        const float* Wh = W1 + head * (CD * CD) + c;
        for (int k = 0; k < 128; ++k) {
            const float w = Wh[k << 7];
            #pragma unroll
            for (int j = 0; j < 4; ++j)
                acc[j] = fmaf(fs[j][k], w, acc[j]);
        }
        const int hc = head * CD + c;
        const float inv = bng[hc] / sqrtf(bnv[hc] + BNEPS);
        const float mu = bnm[hc], be = bnb[hc], bb = b1[hc];
        #pragma unroll
        for (int j = 0; j < 4; ++j) {
            const float hv = (acc[j] + bb - mu) * inv + be;
            as_[h][j][c] = fmaxf(hv, 0.f);
        }
    }
    __syncthreads();

    // ---- GEMM2: 40 independent 128-dots (row j, output slot) ----
    if (tid < 40) {
        const int j = tid / 10;
        const int slot = tid % 10;
        const float* w2; const float* bb2; int hh, o, oc; bool ex = false;
        if (slot < 2)      { w2 = W2c; bb2 = b2c; hh = 0; o = slot;     oc = 2; }
        else if (slot < 3) { w2 = W2z; bb2 = b2z; hh = 1; o = 0;        oc = 1; }
        else if (slot < 6) { w2 = W2d; bb2 = b2d; hh = 2; o = slot - 3; oc = 3; ex = true; }
        else if (slot < 8) { w2 = W2r; bb2 = b2r; hh = 3; o = slot - 6; oc = 2; }
        else               { w2 = W2v; bb2 = b2v; hh = 4; o = slot - 8; oc = 2; }
        float a = 0.f;
        for (int cc = 0; cc < 128; ++cc)
            a = fmaf(as_[hh][j][cc], w2[cc * oc + o], a);
        a += bb2[o];
        if (ex) a = expf(a);
        dec_s[j][slot] = a;
    }
    __syncthreads();

    // ---- decode (stageD formulas, bitwise identical) ----
    if (tid < 4) {
        const int s = s0 + tid;
        const int b = s / KSEL;
        const float score = sel_score[s];
        const int cls = sel_cls[s];
        const int v = sel_vox[s];
        const int n = b * NV + v;
        const float xi = (float)voxel_xy[2 * n];
        const float yi = (float)voxel_xy[2 * n + 1];
        const float* dd = dec_s[tid];
        const float cx = dd[0], cy = dd[1], cz = dd[2];
        const float d0 = dd[3], d1 = dd[4], d2 = dd[5];
        const float rc = dd[6], rs = dd[7], ve0 = dd[8], ve1 = dd[9];
        const float SV = 0.075f * 8.0f;
        const float xs = (xi + cx) * SV + (-54.0f);
        const float ys = (yi + cy) * SV + (-54.0f);
        const float ang = atan2f(rs, rc);
        const bool mk = (xs >= -61.2f) && (ys >= -61.2f) && (cz >= -10.0f) &&
                        (xs <= 61.2f) && (ys <= 61.2f) && (cz <= 10.0f) &&
                        (score > 0.1f);
        const float m = mk ? 1.f : 0.f;
        float* bx = out + (size_t)s * 10;
        bx[0] = xs * m; bx[1] = ys * m; bx[2] = cz * m;
        bx[3] = d0 * m; bx[4] = d1 * m; bx[5] = d2 * m;
        bx[6] = ang * m; bx[7] = ve0 * m; bx[8] = ve1 * m; bx[9] = score * m;
        out[(size_t)total * 10 + s] = mk ? (float)(cls + 1) : 0.f;
        out[(size_t)total * 11 + s] = (float)n;
        out[(size_t)total * 12 + s] = m;
    }
}

extern "C" void kernel_launch(void* const* d_in, const int* in_sizes, int n_in,
                              void* d_out, int out_size, void* d_ws, size_t ws_size,
                              hipStream_t stream) {
    const float* feats   = (const float*)d_in[0];
    const int*   voxelxy = (const int*)d_in[1];
    const float* W1   = (const float*)d_in[2];
    const float* b1   = (const float*)d_in[3];
    const float* bng  = (const float*)d_in[4];
    const float* bnb  = (const float*)d_in[5];
    const float* bnm  = (const float*)d_in[6];
    const float* bnv  = (const float*)d_in[7];
    const float* W2hm = (const float*)d_in[8];
    const float* b2hm = (const float*)d_in[9];
    const float* W2c  = (const float*)d_in[10];
    const float* b2c  = (const float*)d_in[11];
    const float* W2z  = (const float*)d_in[12];
    const float* b2z  = (const float*)d_in[13];
    const float* W2d  = (const float*)d_in[14];
    const float* b2d  = (const float*)d_in[15];
    const float* W2r  = (const float*)d_in[16];
    const float* b2r  = (const float*)d_in[17];
    const float* W2v  = (const float*)d_in[18];
    const float* b2v  = (const float*)d_in[19];

    const int B = in_sizes[0] / (NV * CD);
    const int N = B * NV;
    const int total = B * KSEL;

    // workspace layout (8-byte aligned blocks)
    char* ws = (char*)d_ws;
    unsigned int* scoreb    = (unsigned int*)ws;         ws += (size_t)B * NK * 4;
    unsigned int* hist_part = (unsigned int*)ws;         ws += (size_t)B * NP * H20BINS * 4;
    unsigned int* cnt       = (unsigned int*)ws;         ws += 8 * 4;
    unsigned int* Tbuf      = (unsigned int*)ws;         ws += 8 * 4;
    unsigned long long* cand = (unsigned long long*)ws;  ws += (size_t)B * CANDCAP * 8;
    float* sel_score = (float*)ws;                       ws += (size_t)total * 4;
    int*   sel_cls   = (int*)ws;                         ws += (size_t)total * 4;
    int*   sel_vox   = (int*)ws;                         ws += (size_t)total * 4;

    stageA_kernel<<<dim3(N / 64), dim3(256), 0, stream>>>(
        feats, W1, b1, bng, bnb, bnm, bnv, W2hm, b2hm, scoreb);

    stageB1_kernel<<<dim3(NP, B), dim3(256), 0, stream>>>(scoreb, hist_part);
    stageB2_kernel<<<dim3(B), dim3(1024), 0, stream>>>(hist_part, Tbuf, cnt);
    stageB3_kernel<<<dim3(NP, B), dim3(256), 0, stream>>>(scoreb, Tbuf, cnt, cand);
    stageB4_kernel<<<dim3(B), dim3(1024), 0, stream>>>(
        cand, cnt, sel_score, sel_cls, sel_vox);

    stageCD_kernel<<<dim3(total / 4), dim3(640), 0, stream>>>(
        feats, voxelxy, sel_score, sel_cls, sel_vox,
        W1, b1, bng, bnb, bnm, bnv,
        W2c, b2c, W2z, b2z, W2d, b2d, W2r, b2r, W2v, b2v,
        (float*)d_out, total);
}

// Round 16
// 258.100 us; speedup vs baseline: 1.2571x; 1.0177x over previous
//
#include <hip/hip_runtime.h>
#include <math.h>

#define NV 32768
#define CD 128
#define NCLS 10
#define KSEL 500
#define BNEPS 1e-5f
#define NK (NCLS * NV)          // 327680 keys per batch
#define H20CUT 0x3E000          // (s>>12) floor for score >= 0.125
#define H20BINS 6144            // (0x3F800 - 0x3E000); sigmoid < 1.0
#define CANDCAP 2048
#define NP 32                   // histogram/filter chunks per batch
#define PCHUNKV (NK / NP)       // 10240 keys per chunk
#define PCHUNK4 (PCHUNKV / 4)   // 2560 uint4 per chunk
#define LCAP 512                // per-block LDS candidate list capacity

// ---------------------------------------------------------------------------
// Stage A (r12 champion, 102 µs): 64 rows x 128 cols per block (256 thr),
// 2048 blocks, 8 rows x 4 cols per thread. W-per-fmaf = 0.125 (r11's
// confirmed win); only the GLOBAL W stream is register double-buffered
// (fr inline -> no spill, r12's fix); w2s/b2s in LDS for GEMM2 broadcast.
// fmaf order per (row,col) k-ascending on identical values -> bitwise
// identical scores (absmax 0.0 verified through r12).
// ---------------------------------------------------------------------------
__global__ __launch_bounds__(256, 4) void stageA_kernel(
    const float* __restrict__ feats,
    const float* __restrict__ W1,
    const float* __restrict__ b1,
    const float* __restrict__ bng,
    const float* __restrict__ bnb,
    const float* __restrict__ bnm,
    const float* __restrict__ bnv,
    const float* __restrict__ W2hm,
    const float* __restrict__ b2hm,
    unsigned int* __restrict__ scoreb)
{
    // union: swizzled feats (8192 floats) / act[64][129] (8256 floats)
    __shared__ __align__(16) float smem[64 * 129];
    __shared__ float w2s[CD * NCLS];
    __shared__ float b2s[NCLS];
    float4* const fsmv = (float4*)smem;

    const int tid = threadIdx.x;
    const int gbase = blockIdx.x * 64;

    for (int i = tid; i < CD * NCLS; i += 256) w2s[i] = W2hm[i];
    if (tid < NCLS) b2s[tid] = b2hm[tid];

    // feats tile -> LDS, swizzled: (r, float4-group g) at fsmv[r*32 + (g^(r&31))]
    for (int t = tid; t < 64 * 32; t += 256) {
        const int r = t >> 5;
        const int g = t & 31;
        const float4 v = *(const float4*)(feats + (((size_t)(gbase + r)) << 7) + (g << 2));
        fsmv[r * 32 + (g ^ (r & 31))] = v;
    }
    __syncthreads();

    const int c0 = (tid & 31) << 2;   // 4 output cols (32 col groups)
    const int r0 = (tid >> 5) << 3;   // 8 rows (8 row groups -> 64 rows)
    const float* const Wc0 = W1 + c0;

    float acc[8][4];
    #pragma unroll
    for (int i = 0; i < 8; ++i)
        #pragma unroll
        for (int j = 0; j < 4; ++j) acc[i][j] = 0.f;

    float4 wA[4], wB[4];

    // ---- prologue: W for k-chunk 0 into set A ----
    #pragma unroll
    for (int kk = 0; kk < 4; ++kk)
        wA[kk] = *(const float4*)(Wc0 + (kk << 7));

#define SA_PREFETCH_W(WW, KC)                                             \
    {                                                                     \
        const int kb_ = (KC) << 2;                                        \
        _Pragma("unroll")                                                 \
        for (int kk = 0; kk < 4; ++kk)                                    \
            WW[kk] = *(const float4*)(Wc0 + ((kb_ + kk) << 7));           \
    }

#define SA_COMPUTE(WW, KC)                                                \
    {                                                                     \
        const int kc_ = (KC);                                             \
        float4 fr[8];                                                     \
        _Pragma("unroll")                                                 \
        for (int i = 0; i < 8; ++i) {                                     \
            const int row = r0 + i;                                       \
            fr[i] = fsmv[row * 32 + (kc_ ^ (row & 31))];                  \
        }                                                                 \
        const float* frp = (const float*)fr;                              \
        const float* wp  = (const float*)WW;                              \
        _Pragma("unroll")                                                 \
        for (int kk = 0; kk < 4; ++kk)                                    \
            _Pragma("unroll")                                             \
            for (int ri = 0; ri < 8; ++ri) {                              \
                const float f = frp[ri * 4 + kk];                         \
                _Pragma("unroll")                                         \
                for (int ci = 0; ci < 4; ++ci)                            \
                    acc[ri][ci] = fmaf(f, wp[kk * 4 + ci], acc[ri][ci]);  \
            }                                                             \
    }

    for (int kc = 0; kc < 32; kc += 2) {
        SA_PREFETCH_W(wB, kc + 1)               // kc+1 <= 31 always
        SA_COMPUTE(wA, kc)                      // chunk kc (fr inline)
        SA_PREFETCH_W(wA, (kc + 2) & 31)        // last iter reloads 0 (unused)
        SA_COMPUTE(wB, kc + 1)                  // chunk kc+1
    }
#undef SA_PREFETCH_W
#undef SA_COMPUTE

    __syncthreads(); // all fsm reads done before overwrite with act

    // BN (eval) + ReLU  (identical formulas/order per (row,col))
    #pragma unroll
    for (int ci = 0; ci < 4; ++ci) {
        const int c = c0 + ci;
        const float inv = bng[c] / sqrtf(bnv[c] + BNEPS);
        const float mu = bnm[c];
        const float be = bnb[c];
        const float bb = b1[c];
        #pragma unroll
        for (int ri = 0; ri < 8; ++ri) {
            const float h = (acc[ri][ci] + bb - mu) * inv + be;
            acc[ri][ci] = fmaxf(h, 0.f);
        }
    }
    // act[r][c] with odd stride 129
    #pragma unroll
    for (int ri = 0; ri < 8; ++ri)
        #pragma unroll
        for (int ci = 0; ci < 4; ++ci)
            smem[(r0 + ri) * 129 + c0 + ci] = acc[ri][ci];
    __syncthreads();

    // GEMM2: logits[r][o] = sum_c act[r][c] * W2[c][o]; sequential c order.
    const int r = tid & 63;
    const int ogrp = tid >> 6;  // wave-uniform
    float lg[3] = {0.f, 0.f, 0.f};
    for (int c = 0; c < 128; ++c) {
        const float a = smem[r * 129 + c];
        #pragma unroll
        for (int i = 0; i < 3; ++i) {
            const int o = ogrp + 4 * i;
            if (o < NCLS) lg[i] = fmaf(a, w2s[c * NCLS + o], lg[i]);
        }
    }
    const int n = gbase + r;
    const int b = n >> 15;          // NV = 2^15
    const int v = n & (NV - 1);
    unsigned int* sb = scoreb + (size_t)b * NK;
    #pragma unroll
    for (int i = 0; i < 3; ++i) {
        const int o = ogrp + 4 * i;
        if (o < NCLS) {
            const float x = lg[i] + b2s[o];
            const float s = 1.f / (1.f + expf(-x));
            sb[o * NV + v] = __float_as_uint(s);
        }
    }
}

// ---------------------------------------------------------------------------
// Stage B1: per-chunk PARTIAL 20-bit histograms, plain stores (no global
// atomics, no zeroing kernel). grid (NP, B) = 128 blocks.
// ---------------------------------------------------------------------------
__global__ __launch_bounds__(256) void stageB1_kernel(
    const unsigned int* __restrict__ scoreb,
    unsigned int* __restrict__ hist_part)
{
    __shared__ unsigned int lh[H20BINS];
    const int tid = threadIdx.x;
    const int b = blockIdx.y;
    const uint4* sb4 = (const uint4*)(scoreb + (size_t)b * NK) + (size_t)blockIdx.x * PCHUNK4;

    for (int i = tid; i < H20BINS; i += 256) lh[i] = 0u;
    __syncthreads();

    #pragma unroll
    for (int q = 0; q < 10; ++q) {                // 10*256 = 2560 uint4
        const uint4 v = sb4[q * 256 + tid];
        const unsigned int sv[4] = {v.x, v.y, v.z, v.w};
        #pragma unroll
        for (int k = 0; k < 4; ++k) {
            const int rel = (int)(sv[k] >> 12) - H20CUT;
            if (rel >= 0) atomicAdd(&lh[rel], 1u);
        }
    }
    __syncthreads();

    unsigned int* gh = hist_part + ((size_t)b * NP + blockIdx.x) * H20BINS;
    for (int i = tid; i < H20BINS; i += 256) gh[i] = lh[i];   // ALL bins
}

// ---------------------------------------------------------------------------
// Stage B2: sum partials + suffix-scan -> threshold T (20-bit truncated).
// grid (B), 1024 thr. Also zeroes cnt[b]. Deterministic (fixed sum order).
// ---------------------------------------------------------------------------
__global__ __launch_bounds__(1024) void stageB2_kernel(
    const unsigned int* __restrict__ hist_part,
    unsigned int* __restrict__ Tbuf,
    unsigned int* __restrict__ cnt)
{
    __shared__ unsigned int part[1024];
    __shared__ unsigned int sT;
    const int b = blockIdx.x;
    const int tid = threadIdx.x;  // owns bins [tid*6, tid*6+6)

    unsigned int loc[6] = {0u, 0u, 0u, 0u, 0u, 0u};
    const unsigned int* hp = hist_part + (size_t)b * NP * H20BINS;
    for (int p = 0; p < NP; ++p) {
        const unsigned int* hq = hp + (size_t)p * H20BINS + tid * 6;
        #pragma unroll
        for (int i = 0; i < 6; ++i) loc[i] += hq[i];
    }
    unsigned int Ls = 0;
    #pragma unroll
    for (int i = 0; i < 6; ++i) Ls += loc[i];
    part[tid] = Ls;
    __syncthreads();

    // inclusive suffix scan over 1024 partials (Hillis-Steele, 10 steps)
    for (int off = 1; off < 1024; off <<= 1) {
        const unsigned int add = (tid + off < 1024) ? part[tid + off] : 0u;
        __syncthreads();
        part[tid] += add;
        __syncthreads();
    }
    const unsigned int incl = part[tid];          // sum of segments >= tid
    const unsigned int above_seg = incl - Ls;     // sum of segments  > tid

    if (above_seg < KSEL && incl >= KSEL) {       // exactly one thread
        int above = (int)above_seg;
        int tbin = -1;
        #pragma unroll
        for (int i = 5; i >= 0; --i) {
            const int cbin = (int)loc[i];
            if (tbin < 0) {
                if (above + cbin >= KSEL) tbin = tid * 6 + i;
                else above += cbin;
            }
        }
        sT = ((unsigned int)(tbin + H20CUT)) << 12;
    }
    if (tid == 0 && part[0] < KSEL) sT = ((unsigned int)H20CUT) << 12;  // degenerate
    __syncthreads();
    if (tid == 0) {
        Tbuf[b] = sT;
        cnt[b] = 0u;
    }
}

// ---------------------------------------------------------------------------
// Stage B3: filter s >= T, per-block LDS aggregation -> ONE global atomic
// per block. grid (NP, B) = 128 blocks.
// ---------------------------------------------------------------------------
__global__ __launch_bounds__(256) void stageB3_kernel(
    const unsigned int* __restrict__ scoreb,
    const unsigned int* __restrict__ Tbuf,
    unsigned int* __restrict__ cnt,
    unsigned long long* __restrict__ cand)
{
    __shared__ unsigned long long lbuf[LCAP];
    __shared__ unsigned int lcnt;
    __shared__ unsigned int sbase;
    const int tid = threadIdx.x;
    const int b = blockIdx.y;
    const unsigned int T = Tbuf[b];
    const uint4* sb4 = (const uint4*)(scoreb + (size_t)b * NK) + (size_t)blockIdx.x * PCHUNK4;
    unsigned long long* cb = cand + (size_t)b * CANDCAP;

    if (tid == 0) lcnt = 0u;
    __syncthreads();

    #pragma unroll
    for (int q = 0; q < 10; ++q) {
        const int vi = q * 256 + tid;
        const uint4 v = sb4[vi];
        const unsigned int sv[4] = {v.x, v.y, v.z, v.w};
        const unsigned int i0 = (unsigned int)((blockIdx.x * PCHUNK4 + vi) * 4);
        #pragma unroll
        for (int k = 0; k < 4; ++k) {
            if (sv[k] >= T) {
                const unsigned long long key =
                    ((unsigned long long)sv[k] << 32) |
                    (unsigned long long)(0xFFFFFFFFu - (i0 + k));
                const unsigned int p = atomicAdd(&lcnt, 1u);
                if (p < LCAP) {
                    lbuf[p] = key;
                } else {                           // overflow: direct global
                    const unsigned int gp = atomicAdd(&cnt[b], 1u);
                    if (gp < CANDCAP) cb[gp] = key;
                }
            }
        }
    }
    __syncthreads();
    const unsigned int nloc = min(lcnt, (unsigned int)LCAP);
    if (tid == 0) sbase = (nloc > 0u) ? atomicAdd(&cnt[b], nloc) : 0u;
    __syncthreads();
    const unsigned int base = sbase;
    for (unsigned int i = tid; i < nloc; i += 256) {
        const unsigned int pos = base + i;
        if (pos < CANDCAP) cb[pos] = lbuf[i];
    }
}

// ---------------------------------------------------------------------------
// Stage B4: bitonic sort candidates desc (sized to count), emit top-500.
// grid (B), 1024 thr.
// ---------------------------------------------------------------------------
__global__ __launch_bounds__(1024) void stageB4_kernel(
    const unsigned long long* __restrict__ cand,
    const unsigned int* __restrict__ cnt,
    float* __restrict__ sel_score,
    int* __restrict__ sel_cls,
    int* __restrict__ sel_vox)
{
    __shared__ unsigned long long kbuf[CANDCAP];
    const int b = blockIdx.x;
    const int tid = threadIdx.x;
    const int n = min((int)cnt[b], CANDCAP);
    int m = 512;
    while (m < n) m <<= 1;
    for (int i = tid; i < m; i += 1024)
        kbuf[i] = (i < n) ? cand[(size_t)b * CANDCAP + i] : 0ull;
    __syncthreads();
    for (int size = 2; size <= m; size <<= 1) {
        for (int stride = size >> 1; stride > 0; stride >>= 1) {
            for (int j = tid; j < m; j += 1024) {
                const int p = j ^ stride;
                if (p > j) {
                    const unsigned long long x = kbuf[j];
                    const unsigned long long y = kbuf[p];
                    const bool descRegion = ((j & size) == 0);
                    if ((x < y) == descRegion) { kbuf[j] = y; kbuf[p] = x; }
                }
            }
            __syncthreads();
        }
    }
    if (tid < KSEL) {
        const unsigned long long kk = kbuf[tid];
        const unsigned int s32 = (unsigned int)(kk >> 32);
        const unsigned int fl = 0xFFFFFFFFu - (unsigned int)(kk & 0xFFFFFFFFull);
        const int idx = b * KSEL + tid;
        sel_score[idx] = __uint_as_float(s32);
        sel_cls[idx] = (int)(fl >> 15);
        sel_vox[idx] = (int)(fl & (NV - 1));
    }
}

// ---------------------------------------------------------------------------
// Stage C+D fused, head-parallel: 640 threads = 5 heads x 128 cols; all 5
// head-GEMMs run concurrently. GEMM2 = 40 parallel 128-dots. Per-(row,col)
// k/cc order identical to the verified version -> bitwise identical.
// ---------------------------------------------------------------------------
__global__ __launch_bounds__(640) void stageCD_kernel(
    const float* __restrict__ feats,
    const int* __restrict__ voxel_xy,
    const float* __restrict__ sel_score,
    const int* __restrict__ sel_cls,
    const int* __restrict__ sel_vox,
    const float* __restrict__ W1,
    const float* __restrict__ b1,
    const float* __restrict__ bng,
    const float* __restrict__ bnb,
    const float* __restrict__ bnm,
    const float* __restrict__ bnv,
    const float* __restrict__ W2c, const float* __restrict__ b2c,
    const float* __restrict__ W2z, const float* __restrict__ b2z,
    const float* __restrict__ W2d, const float* __restrict__ b2d,
    const float* __restrict__ W2r, const float* __restrict__ b2r,
    const float* __restrict__ W2v, const float* __restrict__ b2v,
    float* __restrict__ out,
    int total)
{
    __shared__ float fs[4][128];
    __shared__ float as_[5][4][128];
    __shared__ float dec_s[4][10];
    __shared__ int vsel[4];
    const int tid = threadIdx.x;
    const int s0 = blockIdx.x * 4;

    if (tid < 4) {
        const int s = s0 + tid;
        vsel[tid] = (s / KSEL) * NV + sel_vox[s];
    }
    __syncthreads();
    if (tid < 512) {
        const int j = tid >> 7;
        const int c = tid & 127;
        fs[j][c] = feats[((size_t)vsel[j] << 7) + c];
    }
    __syncthreads();

    // ---- GEMM1 + BN + ReLU, all 5 heads concurrent ----
    {
        const int h = tid / 128;       // 0..4 (wave-uniform: 128 = 2 waves)
        const int c = tid & 127;
        const int head = h + 1;
        float acc[4] = {0.f, 0.f, 0.f, 0.f};
        const float* Wh = W1 + head * (CD * CD) + c;
        for (int k = 0; k < 128; ++k) {
            const float w = Wh[k << 7];
            #pragma unroll
            for (int j = 0; j < 4; ++j)
                acc[j] = fmaf(fs[j][k], w, acc[j]);
        }
        const int hc = head * CD + c;
        const float inv = bng[hc] / sqrtf(bnv[hc] + BNEPS);
        const float mu = bnm[hc], be = bnb[hc], bb = b1[hc];
        #pragma unroll
        for (int j = 0; j < 4; ++j) {
            const float hv = (acc[j] + bb - mu) * inv + be;
            as_[h][j][c] = fmaxf(hv, 0.f);
        }
    }
    __syncthreads();

    // ---- GEMM2: 40 independent 128-dots (row j, output slot) ----
    if (tid < 40) {
        const int j = tid / 10;
        const int slot = tid % 10;
        const float* w2; const float* bb2; int hh, o, oc; bool ex = false;
        if (slot < 2)      { w2 = W2c; bb2 = b2c; hh = 0; o = slot;     oc = 2; }
        else if (slot < 3) { w2 = W2z; bb2 = b2z; hh = 1; o = 0;        oc = 1; }
        else if (slot < 6) { w2 = W2d; bb2 = b2d; hh = 2; o = slot - 3; oc = 3; ex = true; }
        else if (slot < 8) { w2 = W2r; bb2 = b2r; hh = 3; o = slot - 6; oc = 2; }
        else               { w2 = W2v; bb2 = b2v; hh = 4; o = slot - 8; oc = 2; }
        float a = 0.f;
        for (int cc = 0; cc < 128; ++cc)
            a = fmaf(as_[hh][j][cc], w2[cc * oc + o], a);
        a += bb2[o];
        if (ex) a = expf(a);
        dec_s[j][slot] = a;
    }
    __syncthreads();

    // ---- decode (stageD formulas, bitwise identical) ----
    if (tid < 4) {
        const int s = s0 + tid;
        const int b = s / KSEL;
        const float score = sel_score[s];
        const int cls = sel_cls[s];
        const int v = sel_vox[s];
        const int n = b * NV + v;
        const float xi = (float)voxel_xy[2 * n];
        const float yi = (float)voxel_xy[2 * n + 1];
        const float* dd = dec_s[tid];
        const float cx = dd[0], cy = dd[1], cz = dd[2];
        const float d0 = dd[3], d1 = dd[4], d2 = dd[5];
        const float rc = dd[6], rs = dd[7], ve0 = dd[8], ve1 = dd[9];
        const float SV = 0.075f * 8.0f;
        const float xs = (xi + cx) * SV + (-54.0f);
        const float ys = (yi + cy) * SV + (-54.0f);
        const float ang = atan2f(rs, rc);
        const bool mk = (xs >= -61.2f) && (ys >= -61.2f) && (cz >= -10.0f) &&
                        (xs <= 61.2f) && (ys <= 61.2f) && (cz <= 10.0f) &&
                        (score > 0.1f);
        const float m = mk ? 1.f : 0.f;
        float* bx = out + (size_t)s * 10;
        bx[0] = xs * m; bx[1] = ys * m; bx[2] = cz * m;
        bx[3] = d0 * m; bx[4] = d1 * m; bx[5] = d2 * m;
        bx[6] = ang * m; bx[7] = ve0 * m; bx[8] = ve1 * m; bx[9] = score * m;
        out[(size_t)total * 10 + s] = mk ? (float)(cls + 1) : 0.f;
        out[(size_t)total * 11 + s] = (float)n;
        out[(size_t)total * 12 + s] = m;
    }
}

extern "C" void kernel_launch(void* const* d_in, const int* in_sizes, int n_in,
                              void* d_out, int out_size, void* d_ws, size_t ws_size,
                              hipStream_t stream) {
    const float* feats   = (const float*)d_in[0];
    const int*   voxelxy = (const int*)d_in[1];
    const float* W1   = (const float*)d_in[2];
    const float* b1   = (const float*)d_in[3];
    const float* bng  = (const float*)d_in[4];
    const float* bnb  = (const float*)d_in[5];
    const float* bnm  = (const float*)d_in[6];
    const float* bnv  = (const float*)d_in[7];
    const float* W2hm = (const float*)d_in[8];
    const float* b2hm = (const float*)d_in[9];
    const float* W2c  = (const float*)d_in[10];
    const float* b2c  = (const float*)d_in[11];
    const float* W2z  = (const float*)d_in[12];
    const float* b2z  = (const float*)d_in[13];
    const float* W2d  = (const float*)d_in[14];
    const float* b2d  = (const float*)d_in[15];
    const float* W2r  = (const float*)d_in[16];
    const float* b2r  = (const float*)d_in[17];
    const float* W2v  = (const float*)d_in[18];
    const float* b2v  = (const float*)d_in[19];

    const int B = in_sizes[0] / (NV * CD);
    const int N = B * NV;
    const int total = B * KSEL;

    // workspace layout (8-byte aligned blocks)
    char* ws = (char*)d_ws;
    unsigned int* scoreb    = (unsigned int*)ws;         ws += (size_t)B * NK * 4;
    unsigned int* hist_part = (unsigned int*)ws;         ws += (size_t)B * NP * H20BINS * 4;
    unsigned int* cnt       = (unsigned int*)ws;         ws += 8 * 4;
    unsigned int* Tbuf      = (unsigned int*)ws;         ws += 8 * 4;
    unsigned long long* cand = (unsigned long long*)ws;  ws += (size_t)B * CANDCAP * 8;
    float* sel_score = (float*)ws;                       ws += (size_t)total * 4;
    int*   sel_cls   = (int*)ws;                         ws += (size_t)total * 4;
    int*   sel_vox   = (int*)ws;                         ws += (size_t)total * 4;

    stageA_kernel<<<dim3(N / 64), dim3(256), 0, stream>>>(
        feats, W1, b1, bng, bnb, bnm, bnv, W2hm, b2hm, scoreb);

    stageB1_kernel<<<dim3(NP, B), dim3(256), 0, stream>>>(scoreb, hist_part);
    stageB2_kernel<<<dim3(B), dim3(1024), 0, stream>>>(hist_part, Tbuf, cnt);
    stageB3_kernel<<<dim3(NP, B), dim3(256), 0, stream>>>(scoreb, Tbuf, cnt, cand);
    stageB4_kernel<<<dim3(B), dim3(1024), 0, stream>>>(
        cand, cnt, sel_score, sel_cls, sel_vox);

    stageCD_kernel<<<dim3(total / 4), dim3(640), 0, stream>>>(
        feats, voxelxy, sel_score, sel_cls, sel_vox,
        W1, b1, bng, bnb, bnm, bnv,
        W2c, b2c, W2z, b2z, W2d, b2d, W2r, b2r, W2v, b2v,
        (float*)d_out, total);
}